// Round 4
// baseline (414.703 us; speedup 1.0000x reference)
//
#include <hip/hip_runtime.h>

typedef short short8 __attribute__((ext_vector_type(8)));
typedef float float4v __attribute__((ext_vector_type(4)));
typedef unsigned short u16;
typedef unsigned int u32;

#define T_LEN 4096
#define DDIM 512
#define BATCH 8
#define MROWS 32768
#define CH 64
#define NC 64   // T_LEN / CH

__device__ __forceinline__ u16 f2b(float x) {
    unsigned u = __float_as_uint(x);
    unsigned r = (u + 0x7FFFu + ((u >> 16) & 1u)) >> 16;
    return (u16)r;
}
// fast activations: v_exp_f32 + v_rcp_f32 (≈1ulp, invisible at bf16)
__device__ __forceinline__ float sigm(float x) {
    return __builtin_amdgcn_rcpf(1.f + __builtin_amdgcn_exp2f(-1.44269504f * x));
}
__device__ __forceinline__ float tanh_fast(float x) {
    return 1.f - 2.f * __builtin_amdgcn_rcpf(1.f + __builtin_amdgcn_exp2f(2.88539008f * x));
}
__device__ __forceinline__ float blo(u32 u) { return __uint_as_float(u << 16); }
__device__ __forceinline__ float bhi(u32 u) { return __uint_as_float(u & 0xFFFF0000u); }
__device__ __forceinline__ u32 pack2(float a, float b) {
    return (u32)f2b(a) | ((u32)f2b(b) << 16);
}

__device__ __forceinline__ void gl2lds16(const u16* g, u16* l) {
    __builtin_amdgcn_global_load_lds(
        (const __attribute__((address_space(1))) void*)g,
        (__attribute__((address_space(3))) void*)l, 16, 0, 0);
}

// ---------------- converts ----------------
__global__ __launch_bounds__(256) void cvt_x(const float* __restrict__ x,
                                             u16* __restrict__ xb, size_t n) {
    size_t i = ((size_t)blockIdx.x * 256 + threadIdx.x) * 4;
    if (i < n) {
        float4v v = *(const float4v*)&x[i];
        ushort4 p;
        p.x = f2b(v[0]); p.y = f2b(v[1]); p.z = f2b(v[2]); p.w = f2b(v[3]);
        *(ushort4*)&xb[i] = p;
    }
}

// Wt[j][k] = W[e][k][h], j = e*512+h
__global__ __launch_bounds__(256) void cvt_wt(const float* __restrict__ W,
                                              u16* __restrict__ Wt, int N) {
    int idx = blockIdx.x * 256 + threadIdx.x;
    if (idx >= N * 512) return;
    int j = idx >> 9;
    int k = idx & 511;
    int e = j >> 9, h = j & 511;
    Wt[(size_t)j * 512 + k] = f2b(W[((size_t)e * 512 + k) * 512 + h]);
}

// ---------------- GEMM + activation epilogue ----------------
// Fragment-order LDS: subtile t (16 rows), lane l -> u16 slot t*512 + l*8,
// holding global row (t*16 + (l&15)), k-chunk (l>>4)*8. Consumer ds_read_b128
// is lane-linear => ZERO bank conflicts; global_load_lds dest stays linear
// (per-lane global source carries the permutation).
// MODE 1: N=1024: tanh -> o0(v) bf16 | sigmoid -> o1(f1) bf16
// MODE 2: N=2048: f2->o0, i->o1, o->o2 (sigm), z->o3 (tanh), all bf16
// MODE 3: N=512 : raw + bias -> o0 (f32)
template <int MODE>
__global__ __launch_bounds__(256) void gemm_act(
    const u16* __restrict__ A, const u16* __restrict__ Bt,
    const float* __restrict__ bias, void* __restrict__ o0v,
    void* __restrict__ o1v, void* __restrict__ o2v, void* __restrict__ o3v) {
    constexpr int K = 512;
    constexpr int NKT = K / 32;       // 16
    constexpr int LBUF = 128 * 32;    // u16 elems per buffer
    __shared__ u16 lsA[2][LBUF];
    __shared__ u16 lsB[2][LBUF];
    const int tid = threadIdx.x;
    const int lane = tid & 63;
    const int wid = tid >> 6;
    const int wr = wid >> 1, wc = wid & 1;
    const int l0 = lane & 15, lh = lane >> 4;
    const int bn0 = blockIdx.x * 128;
    const int bm0 = blockIdx.y * 128;

    // staging addresses: thread covers flat = tid and tid+256, flat in [0,512)
    // flat -> subtile t = flat>>6, lane-slot l = flat&63
    // global: row t*16 + (l&15), k-chunk (l>>4)*8 ; LDS: flat*8 (u16)
    const int t0 = tid >> 6, sl0 = tid & 63;
    const int t1 = (tid + 256) >> 6, sl1 = tid & 63;  // (tid+256)&63 == tid&63
    const int ar0 = t0 * 16 + (sl0 & 15), ac0 = (sl0 >> 4) * 8;
    const int ar1 = t1 * 16 + (sl1 & 15), ac1 = (sl1 >> 4) * 8;
    const u16* gA0 = &A[(size_t)(bm0 + ar0) * K + ac0];
    const u16* gA1 = &A[(size_t)(bm0 + ar1) * K + ac1];
    const u16* gB0 = &Bt[(size_t)(bn0 + ar0) * K + ac0];
    const u16* gB1 = &Bt[(size_t)(bn0 + ar1) * K + ac1];
    u16* dA0 = &lsA[0][tid * 8];
    u16* dA1 = &lsA[0][(tid + 256) * 8];
    u16* dB0 = &lsB[0][tid * 8];
    u16* dB1 = &lsB[0][(tid + 256) * 8];

    float4v acc[4][4];
#pragma unroll
    for (int m = 0; m < 4; ++m)
#pragma unroll
        for (int n = 0; n < 4; ++n) acc[m][n] = (float4v){0.f, 0.f, 0.f, 0.f};

    // prologue: stage kt=0 into buf 0
    gl2lds16(gA0, dA0);
    gl2lds16(gA1, dA1);
    gl2lds16(gB0, dB0);
    gl2lds16(gB1, dB1);
    __syncthreads();

#pragma unroll
    for (int kt = 0; kt < NKT; ++kt) {
        const int cur = kt & 1, nxt = cur ^ 1;
        // issue next-tile loads FIRST — latency hides under ds_read+MFMA
        if (kt + 1 < NKT) {
            const int off = (kt + 1) * 32;
            gl2lds16(gA0 + off, dA0 + nxt * LBUF);
            gl2lds16(gA1 + off, dA1 + nxt * LBUF);
            gl2lds16(gB0 + off, dB0 + nxt * LBUF);
            gl2lds16(gB1 + off, dB1 + nxt * LBUF);
        }
        short8 af[4], bf[4];
#pragma unroll
        for (int m = 0; m < 4; ++m)
            af[m] = *(const short8*)&lsA[cur][(wr * 4 + m) * 512 + lane * 8];
#pragma unroll
        for (int n = 0; n < 4; ++n)
            bf[n] = *(const short8*)&lsB[cur][(wc * 4 + n) * 512 + lane * 8];
        __builtin_amdgcn_s_setprio(1);
#pragma unroll
        for (int m = 0; m < 4; ++m)
#pragma unroll
            for (int n = 0; n < 4; ++n)
                acc[m][n] = __builtin_amdgcn_mfma_f32_16x16x32_bf16(
                    af[m], bf[n], acc[m][n], 0, 0, 0);
        __builtin_amdgcn_s_setprio(0);
        __syncthreads();
    }

#pragma unroll
    for (int m = 0; m < 4; ++m) {
#pragma unroll
        for (int n = 0; n < 4; ++n) {
            int col = bn0 + wc * 64 + n * 16 + l0;
            float bv = bias[col];
#pragma unroll
            for (int r = 0; r < 4; ++r) {
                int rw = bm0 + wr * 64 + m * 16 + lh * 4 + r;
                float u = acc[m][n][r] + bv;
                size_t oidx = (size_t)rw * 512 + (col & 511);
                if (MODE == 1) {
                    if (col < 512)
                        ((u16*)o0v)[oidx] = f2b(tanh_fast(u));
                    else
                        ((u16*)o1v)[oidx] = f2b(sigm(u));
                } else if (MODE == 2) {
                    int e = col >> 9;
                    if (e == 0)
                        ((u16*)o0v)[oidx] = f2b(sigm(u));
                    else if (e == 1)
                        ((u16*)o1v)[oidx] = f2b(sigm(u));
                    else if (e == 2)
                        ((u16*)o2v)[oidx] = f2b(sigm(u));
                    else
                        ((u16*)o3v)[oidx] = f2b(tanh_fast(u));
                } else {
                    ((float*)o0v)[oidx] = u;
                }
            }
        }
    }
}

// ---------------- chunked scan (bf16 streams, f32 state) ----------------
// carries in [chunk][b*512+d] layout => coalesced in all three passes
template <int S>
__global__ __launch_bounds__(256) void scan_p1(const u16* __restrict__ f,
                                               const u16* __restrict__ v,
                                               const u16* __restrict__ z,
                                               float* __restrict__ cA,
                                               float* __restrict__ cB) {
    int d0 = threadIdx.x * 2;
    int c = blockIdx.x & (NC - 1);
    int b = blockIdx.x >> 6;
    size_t base = ((size_t)b * T_LEN + c * CH) * DDIM + d0;
    float A0 = 1.f, B0 = 0.f, A1 = 1.f, B1 = 0.f;
    for (int t = 0; t < CH; ++t) {
        u32 fu = *(const u32*)&f[base];
        u32 vu = *(const u32*)&v[base];
        float f0 = blo(fu), f1 = bhi(fu);
        float g0 = (1.f - f0) * blo(vu), g1 = (1.f - f1) * bhi(vu);
        if (S == 2) {
            u32 zu = *(const u32*)&z[base];
            g0 *= blo(zu);
            g1 *= bhi(zu);
        }
        B0 = f0 * B0 + g0; A0 *= f0;
        B1 = f1 * B1 + g1; A1 *= f1;
        base += DDIM;
    }
    size_t ci = (size_t)c * 4096 + b * DDIM + d0;
    cA[ci] = A0; cB[ci] = B0;
    cA[ci + 1] = A1; cB[ci + 1] = B1;
}

__global__ __launch_bounds__(256) void scan_p2(float* __restrict__ cA,
                                               const float* __restrict__ cB) {
    int ln = blockIdx.x * 256 + threadIdx.x;  // 0..4095 = b*512+d
    float h = 0.f;
    for (int c = 0; c < NC; ++c) {
        size_t ix = (size_t)c * 4096 + ln;
        float a = cA[ix], bb = cB[ix];
        cA[ix] = h;  // exclusive carry-in
        h = a * h + bb;
    }
}

template <int S>
__global__ __launch_bounds__(256) void scan_p3(
    const u16* __restrict__ f, const u16* __restrict__ v,
    const u16* __restrict__ z, const u16* __restrict__ o,
    const float* __restrict__ cA, u16* __restrict__ hb,
    float* __restrict__ hid) {
    int d0 = threadIdx.x * 2;
    int c = blockIdx.x & (NC - 1);
    int b = blockIdx.x >> 6;
    size_t base = ((size_t)b * T_LEN + c * CH) * DDIM + d0;
    size_t ci = (size_t)c * 4096 + b * DDIM + d0;
    float h0 = cA[ci], h1 = cA[ci + 1];
    for (int t = 0; t < CH; ++t) {
        u32 fu = *(const u32*)&f[base];
        u32 vu = *(const u32*)&v[base];
        float f0 = blo(fu), f1 = bhi(fu);
        float g0 = (1.f - f0) * blo(vu), g1 = (1.f - f1) * bhi(vu);
        if (S == 2) {
            u32 zu = *(const u32*)&z[base];
            g0 *= blo(zu);
            g1 *= bhi(zu);
        }
        h0 = f0 * h0 + g0;
        h1 = f1 * h1 + g1;
        float w0 = h0, w1 = h1;
        if (S == 2) {
            u32 ou = *(const u32*)&o[base];
            w0 *= blo(ou);
            w1 *= bhi(ou);
        }
        *(u32*)&hb[base] = pack2(w0, w1);
        base += DDIM;
    }
    if (c == NC - 1) {
        hid[b * 1024 + (S == 1 ? 0 : 512) + d0] = h0;
        hid[b * 1024 + (S == 1 ? 0 : 512) + d0 + 1] = h1;
    }
}

// ---------------- launch ----------------
extern "C" void kernel_launch(void* const* d_in, const int* in_sizes, int n_in,
                              void* d_out, int out_size, void* d_ws,
                              size_t ws_size, hipStream_t stream) {
    const float* x = (const float*)d_in[0];
    const float* W_in = (const float*)d_in[1];
    const float* b_in = (const float*)d_in[2];
    const float* W_mid = (const float*)d_in[3];
    const float* b_mid = (const float*)d_in[4];
    const float* W_out = (const float*)d_in[5];
    const float* b_out = (const float*)d_in[6];
    float* out = (float*)d_out;
    char* ws = (char*)d_ws;

    const size_t MB = 1u << 20;
    const size_t MD = (size_t)MROWS * DDIM;  // 16.7M elems

    u16* wt_in = (u16*)(ws);              // 1 MB
    u16* wt_mid = (u16*)(ws + 1 * MB);    // 2 MB
    u16* wt_out = (u16*)(ws + 3 * MB);    // 0.5 MB
    u16* hb = (u16*)(ws + 4 * MB);        // 32 MB (xb -> h1 -> s)
    u16* S0 = (u16*)(ws + 36 * MB);       // 32 MB
    u16* S1 = (u16*)(ws + 68 * MB);       // 32 MB
    u16* S2 = (u16*)(ws + 100 * MB);      // 32 MB
    u16* S3 = (u16*)(ws + 132 * MB);      // 32 MB
    float* cA = (float*)(ws + 164 * MB);  // 1 MB
    float* cB = (float*)(ws + 165 * MB);  // 1 MB
    float* hid = out + MD;

    cvt_x<<<(int)(MD / 4 / 256), 256, 0, stream>>>(x, hb, MD);
    cvt_wt<<<(1024 * 512) / 256, 256, 0, stream>>>(W_in, wt_in, 1024);
    cvt_wt<<<(2048 * 512) / 256, 256, 0, stream>>>(W_mid, wt_mid, 2048);
    cvt_wt<<<(512 * 512) / 256, 256, 0, stream>>>(W_out, wt_out, 512);

    // GEMM1: v(S0)=tanh, f1(S1)=sigmoid
    gemm_act<1><<<dim3(8, 256), 256, 0, stream>>>(hb, wt_in, b_in, S0, S1,
                                                  nullptr, nullptr);
    // scan1: h1 = scan(f1, (1-f1)*v) -> hb bf16; hidden_pre
    scan_p1<1><<<512, 256, 0, stream>>>(S1, S0, nullptr, cA, cB);
    scan_p2<<<16, 256, 0, stream>>>(cA, cB);
    scan_p3<1><<<512, 256, 0, stream>>>(S1, S0, nullptr, nullptr, cA, hb, hid);

    // GEMM2: f2(S0), i(S1), o(S2), z(S3)
    gemm_act<2><<<dim3(16, 256), 256, 0, stream>>>(hb, wt_mid, b_mid, S0, S1,
                                                   S2, S3);
    // scan2: h2 = scan(f2, (1-f2)*i*z); s = h2*o -> hb bf16; hidden_middle
    scan_p1<2><<<512, 256, 0, stream>>>(S0, S1, S3, cA, cB);
    scan_p2<<<16, 256, 0, stream>>>(cA, cB);
    scan_p3<2><<<512, 256, 0, stream>>>(S0, S1, S3, S2, cA, hb, hid);

    // GEMM3: out = s@W_out + b_out (f32)
    gemm_act<3><<<dim3(4, 256), 256, 0, stream>>>(hb, wt_out, b_out, out,
                                                  nullptr, nullptr, nullptr);
}

// Round 5
// 345.351 us; speedup vs baseline: 1.2008x; 1.2008x over previous
//
#include <hip/hip_runtime.h>

typedef short short8 __attribute__((ext_vector_type(8)));
typedef float float4v __attribute__((ext_vector_type(4)));
typedef unsigned short u16;
typedef unsigned int u32;

#define T_LEN 4096
#define DDIM 512
#define BATCH 8
#define MROWS 32768
#define CH 64
#define NC 64   // T_LEN / CH

__device__ __forceinline__ u16 f2b(float x) {
    unsigned u = __float_as_uint(x);
    unsigned r = (u + 0x7FFFu + ((u >> 16) & 1u)) >> 16;
    return (u16)r;
}
__device__ __forceinline__ float sigm(float x) {
    return __builtin_amdgcn_rcpf(1.f + __builtin_amdgcn_exp2f(-1.44269504f * x));
}
__device__ __forceinline__ float tanh_fast(float x) {
    return 1.f - 2.f * __builtin_amdgcn_rcpf(1.f + __builtin_amdgcn_exp2f(2.88539008f * x));
}
__device__ __forceinline__ float blo(u32 u) { return __uint_as_float(u << 16); }
__device__ __forceinline__ float bhi(u32 u) { return __uint_as_float(u & 0xFFFF0000u); }
__device__ __forceinline__ u32 pack2(float a, float b) {
    return (u32)f2b(a) | ((u32)f2b(b) << 16);
}

__device__ __forceinline__ void gl2lds16(const u16* g, u16* l) {
    __builtin_amdgcn_global_load_lds(
        (const __attribute__((address_space(1))) void*)g,
        (__attribute__((address_space(3))) void*)l, 16, 0, 0);
}

// ---------------- converts ----------------
__global__ __launch_bounds__(256) void cvt_x(const float* __restrict__ x,
                                             u16* __restrict__ xb, size_t n) {
    size_t i = ((size_t)blockIdx.x * 256 + threadIdx.x) * 4;
    if (i < n) {
        float4v v = *(const float4v*)&x[i];
        ushort4 p;
        p.x = f2b(v[0]); p.y = f2b(v[1]); p.z = f2b(v[2]); p.w = f2b(v[3]);
        *(ushort4*)&xb[i] = p;
    }
}

// Wt[j][k] = W[e][k][h], j = e*512+h
__global__ __launch_bounds__(256) void cvt_wt(const float* __restrict__ W,
                                              u16* __restrict__ Wt, int N) {
    int idx = blockIdx.x * 256 + threadIdx.x;
    if (idx >= N * 512) return;
    int j = idx >> 9;
    int k = idx & 511;
    int e = j >> 9, h = j & 511;
    Wt[(size_t)j * 512 + k] = f2b(W[((size_t)e * 512 + k) * 512 + h]);
}

// ---------------- GEMM + activation epilogue ----------------
// 256x256 block tile, 8 waves (2M x 4N), wave tile 128x64 (8x4 acc of 16x16x32).
// BK=64: LDS rows of 128B, chunk(16B) swizzle c' = c ^ (row&7):
//   - staging keeps LDS dest linear; global source permutes chunks WITHIN a
//     row's 128B span -> coalescing preserved (8-lane runs = 128B contiguous)
//   - ds_read_b128 fragment reads spread uniformly over all 32 banks
// MODE 1: N=1024: tanh -> o0(v) bf16 | sigmoid -> o1(f1) bf16
// MODE 2: N=2048: f2->o0, i->o1, o->o2 (sigm), z->o3 (tanh), all bf16
// MODE 3: N=512 : raw + bias -> o0 (f32)
template <int MODE>
__global__ __launch_bounds__(512) void gemm_act(
    const u16* __restrict__ A, const u16* __restrict__ Bt,
    const float* __restrict__ bias, void* __restrict__ o0v,
    void* __restrict__ o1v, void* __restrict__ o2v, void* __restrict__ o3v) {
    constexpr int K = 512;
    constexpr int BK = 64;            // K-step (u16)
    constexpr int NKT = K / BK;       // 8
    constexpr int LBUF = 256 * 64;    // u16 per buffer (32KB)
    __shared__ u16 lsA[2][LBUF];
    __shared__ u16 lsB[2][LBUF];
    const int tid = threadIdx.x;
    const int lane = tid & 63;
    const int wid = tid >> 6;         // 0..7
    const int wr = wid >> 2;          // 0..1  (M)
    const int wc = wid & 3;           // 0..3  (N)
    const int l0 = lane & 15, lh = lane >> 4;
    const int bn0 = blockIdx.x * 256;
    const int bm0 = blockIdx.y * 256;

    // staging: 4 instrs each for A,B; instr i covers LDS bytes [i*8K, i*8K+8K)
    // LDS slot (r, cc): r = i*64 + (tid>>3), cc = tid&7 ; holds global chunk
    // c = cc ^ (r&7) of row r  -> global addr stays within row's 128B span
    const int sr = tid >> 3;           // row-within-64 per instr
    const int scc = tid & 7;
    float4v acc[8][4];
#pragma unroll
    for (int m = 0; m < 8; ++m)
#pragma unroll
        for (int n = 0; n < 4; ++n) acc[m][n] = (float4v){0.f, 0.f, 0.f, 0.f};

    // per-instr global row and source chunk
    int grow[4], gch[4];
#pragma unroll
    for (int i = 0; i < 4; ++i) {
        grow[i] = i * 64 + sr;
        gch[i] = (scc ^ (grow[i] & 7)) * 8;  // u16 offset within row's BK span
    }

#define STAGE(buf, kt)                                                        \
    {                                                                         \
        const int k0 = (kt) * BK;                                             \
        _Pragma("unroll") for (int i = 0; i < 4; ++i) {                       \
            gl2lds16(&A[(size_t)(bm0 + grow[i]) * K + k0 + gch[i]],           \
                     &lsA[buf][(i * 512 + tid) * 8]);                         \
            gl2lds16(&Bt[(size_t)(bn0 + grow[i]) * K + k0 + gch[i]],          \
                     &lsB[buf][(i * 512 + tid) * 8]);                         \
        }                                                                     \
    }

    STAGE(0, 0);
    __syncthreads();

    for (int kt = 0; kt < NKT; ++kt) {
        const int cur = kt & 1, nxt = cur ^ 1;
        if (kt + 1 < NKT) STAGE(nxt, kt + 1);
#pragma unroll
        for (int kk = 0; kk < 2; ++kk) {
            short8 af[8], bf[4];
            const int cw = kk * 4 + lh;  // wanted chunk
#pragma unroll
            for (int m = 0; m < 8; ++m) {
                int r = wr * 128 + m * 16 + l0;
                af[m] = *(const short8*)&lsA[cur][r * 64 + ((cw ^ (r & 7)) * 8)];
            }
#pragma unroll
            for (int n = 0; n < 4; ++n) {
                int r = wc * 64 + n * 16 + l0;
                bf[n] = *(const short8*)&lsB[cur][r * 64 + ((cw ^ (r & 7)) * 8)];
            }
            __builtin_amdgcn_s_setprio(1);
#pragma unroll
            for (int m = 0; m < 8; ++m)
#pragma unroll
                for (int n = 0; n < 4; ++n)
                    acc[m][n] = __builtin_amdgcn_mfma_f32_16x16x32_bf16(
                        af[m], bf[n], acc[m][n], 0, 0, 0);
            __builtin_amdgcn_s_setprio(0);
        }
        __syncthreads();
    }
#undef STAGE

#pragma unroll
    for (int m = 0; m < 8; ++m) {
#pragma unroll
        for (int n = 0; n < 4; ++n) {
            int col = bn0 + wc * 64 + n * 16 + l0;
            float bv = bias[col];
#pragma unroll
            for (int r = 0; r < 4; ++r) {
                int rw = bm0 + wr * 128 + m * 16 + lh * 4 + r;
                float u = acc[m][n][r] + bv;
                size_t oidx = (size_t)rw * 512 + (col & 511);
                if (MODE == 1) {
                    if (col < 512)
                        ((u16*)o0v)[oidx] = f2b(tanh_fast(u));
                    else
                        ((u16*)o1v)[oidx] = f2b(sigm(u));
                } else if (MODE == 2) {
                    int e = col >> 9;
                    if (e == 0)
                        ((u16*)o0v)[oidx] = f2b(sigm(u));
                    else if (e == 1)
                        ((u16*)o1v)[oidx] = f2b(sigm(u));
                    else if (e == 2)
                        ((u16*)o2v)[oidx] = f2b(sigm(u));
                    else
                        ((u16*)o3v)[oidx] = f2b(tanh_fast(u));
                } else {
                    ((float*)o0v)[oidx] = u;
                }
            }
        }
    }
}

// ---------------- chunked scan (bf16 streams, f32 state) ----------------
template <int S>
__global__ __launch_bounds__(256) void scan_p1(const u16* __restrict__ f,
                                               const u16* __restrict__ v,
                                               const u16* __restrict__ z,
                                               float* __restrict__ cA,
                                               float* __restrict__ cB) {
    int d0 = threadIdx.x * 2;
    int c = blockIdx.x & (NC - 1);
    int b = blockIdx.x >> 6;
    size_t base = ((size_t)b * T_LEN + c * CH) * DDIM + d0;
    float A0 = 1.f, B0 = 0.f, A1 = 1.f, B1 = 0.f;
    for (int t = 0; t < CH; ++t) {
        u32 fu = *(const u32*)&f[base];
        u32 vu = *(const u32*)&v[base];
        float f0 = blo(fu), f1 = bhi(fu);
        float g0 = (1.f - f0) * blo(vu), g1 = (1.f - f1) * bhi(vu);
        if (S == 2) {
            u32 zu = *(const u32*)&z[base];
            g0 *= blo(zu);
            g1 *= bhi(zu);
        }
        B0 = f0 * B0 + g0; A0 *= f0;
        B1 = f1 * B1 + g1; A1 *= f1;
        base += DDIM;
    }
    size_t ci = (size_t)c * 4096 + b * DDIM + d0;
    cA[ci] = A0; cB[ci] = B0;
    cA[ci + 1] = A1; cB[ci + 1] = B1;
}

__global__ __launch_bounds__(256) void scan_p2(float* __restrict__ cA,
                                               const float* __restrict__ cB) {
    int ln = blockIdx.x * 256 + threadIdx.x;  // 0..4095 = b*512+d
    float h = 0.f;
    for (int c = 0; c < NC; ++c) {
        size_t ix = (size_t)c * 4096 + ln;
        float a = cA[ix], bb = cB[ix];
        cA[ix] = h;  // exclusive carry-in
        h = a * h + bb;
    }
}

template <int S>
__global__ __launch_bounds__(256) void scan_p3(
    const u16* __restrict__ f, const u16* __restrict__ v,
    const u16* __restrict__ z, const u16* __restrict__ o,
    const float* __restrict__ cA, u16* __restrict__ hb,
    float* __restrict__ hid) {
    int d0 = threadIdx.x * 2;
    int c = blockIdx.x & (NC - 1);
    int b = blockIdx.x >> 6;
    size_t base = ((size_t)b * T_LEN + c * CH) * DDIM + d0;
    size_t ci = (size_t)c * 4096 + b * DDIM + d0;
    float h0 = cA[ci], h1 = cA[ci + 1];
    for (int t = 0; t < CH; ++t) {
        u32 fu = *(const u32*)&f[base];
        u32 vu = *(const u32*)&v[base];
        float f0 = blo(fu), f1 = bhi(fu);
        float g0 = (1.f - f0) * blo(vu), g1 = (1.f - f1) * bhi(vu);
        if (S == 2) {
            u32 zu = *(const u32*)&z[base];
            g0 *= blo(zu);
            g1 *= bhi(zu);
        }
        h0 = f0 * h0 + g0;
        h1 = f1 * h1 + g1;
        float w0 = h0, w1 = h1;
        if (S == 2) {
            u32 ou = *(const u32*)&o[base];
            w0 *= blo(ou);
            w1 *= bhi(ou);
        }
        *(u32*)&hb[base] = pack2(w0, w1);
        base += DDIM;
    }
    if (c == NC - 1) {
        hid[b * 1024 + (S == 1 ? 0 : 512) + d0] = h0;
        hid[b * 1024 + (S == 1 ? 0 : 512) + d0 + 1] = h1;
    }
}

// ---------------- launch ----------------
extern "C" void kernel_launch(void* const* d_in, const int* in_sizes, int n_in,
                              void* d_out, int out_size, void* d_ws,
                              size_t ws_size, hipStream_t stream) {
    const float* x = (const float*)d_in[0];
    const float* W_in = (const float*)d_in[1];
    const float* b_in = (const float*)d_in[2];
    const float* W_mid = (const float*)d_in[3];
    const float* b_mid = (const float*)d_in[4];
    const float* W_out = (const float*)d_in[5];
    const float* b_out = (const float*)d_in[6];
    float* out = (float*)d_out;
    char* ws = (char*)d_ws;

    const size_t MB = 1u << 20;
    const size_t MD = (size_t)MROWS * DDIM;  // 16.7M elems

    u16* wt_in = (u16*)(ws);              // 1 MB
    u16* wt_mid = (u16*)(ws + 1 * MB);    // 2 MB
    u16* wt_out = (u16*)(ws + 3 * MB);    // 0.5 MB
    u16* hb = (u16*)(ws + 4 * MB);        // 32 MB (xb -> h1 -> s)
    u16* S0 = (u16*)(ws + 36 * MB);       // 32 MB
    u16* S1 = (u16*)(ws + 68 * MB);       // 32 MB
    u16* S2 = (u16*)(ws + 100 * MB);      // 32 MB
    u16* S3 = (u16*)(ws + 132 * MB);      // 32 MB
    float* cA = (float*)(ws + 164 * MB);  // 1 MB
    float* cB = (float*)(ws + 165 * MB);  // 1 MB
    float* hid = out + MD;

    cvt_x<<<(int)(MD / 4 / 256), 256, 0, stream>>>(x, hb, MD);
    cvt_wt<<<(1024 * 512) / 256, 256, 0, stream>>>(W_in, wt_in, 1024);
    cvt_wt<<<(2048 * 512) / 256, 256, 0, stream>>>(W_mid, wt_mid, 2048);
    cvt_wt<<<(512 * 512) / 256, 256, 0, stream>>>(W_out, wt_out, 512);

    // GEMM1: v(S0)=tanh, f1(S1)=sigmoid
    gemm_act<1><<<dim3(4, 128), 512, 0, stream>>>(hb, wt_in, b_in, S0, S1,
                                                  nullptr, nullptr);
    // scan1: h1 = scan(f1, (1-f1)*v) -> hb bf16; hidden_pre
    scan_p1<1><<<512, 256, 0, stream>>>(S1, S0, nullptr, cA, cB);
    scan_p2<<<16, 256, 0, stream>>>(cA, cB);
    scan_p3<1><<<512, 256, 0, stream>>>(S1, S0, nullptr, nullptr, cA, hb, hid);

    // GEMM2: f2(S0), i(S1), o(S2), z(S3)
    gemm_act<2><<<dim3(8, 128), 512, 0, stream>>>(hb, wt_mid, b_mid, S0, S1,
                                                  S2, S3);
    // scan2: h2 = scan(f2, (1-f2)*i*z); s = h2*o -> hb bf16; hidden_middle
    scan_p1<2><<<512, 256, 0, stream>>>(S0, S1, S3, cA, cB);
    scan_p2<<<16, 256, 0, stream>>>(cA, cB);
    scan_p3<2><<<512, 256, 0, stream>>>(S0, S1, S3, S2, cA, hb, hid);

    // GEMM3: out = s@W_out + b_out (f32)
    gemm_act<3><<<dim3(2, 128), 512, 0, stream>>>(hb, wt_out, b_out, out,
                                                  nullptr, nullptr, nullptr);
}